// Round 3
// baseline (3412.054 us; speedup 1.0000x reference)
//
#include <hip/hip_runtime.h>

#define N_B 256
#define T_SEQ 32
#define DD 1024
#define HH 1024

typedef short short8 __attribute__((ext_vector_type(8)));
typedef float floatx4 __attribute__((ext_vector_type(4)));
typedef unsigned short ushort_t;

// ---- scratch as device globals (no dependence on ws_size) ------------------
__device__ __align__(16) ushort_t g_Wxt[(size_t)4096 * 1024];        // 8 MB  [j][k] = Wx^T
__device__ __align__(16) ushort_t g_W2 [(size_t)4096 * 2048];        // 16 MB [j][k] = [Wh^T | Wattn^T]
__device__ __align__(16) ushort_t g_xb [(size_t)N_B * T_SEQ * DD];   // 16 MB bf16 x
__device__ __align__(16) float    g_px [(size_t)T_SEQ * N_B * 4096]; // 134 MB [t][n][j] = x@Wx + b
__device__ __align__(16) ushort_t g_Hc[2][N_B * 2048];               // [h | attn] bf16
__device__ __align__(16) float    g_c [N_B * HH];                    // fp32 cell state

__device__ __forceinline__ float bf2f(ushort_t u){
    union { unsigned int i; float f; } v; v.i = ((unsigned int)u) << 16; return v.f;
}
__device__ __forceinline__ ushort_t f2bf(float f){
    union { unsigned int i; float f; } v; v.f = f;
    unsigned int i = v.i;
    unsigned int r = (i + 0x7FFFu + ((i >> 16) & 1u)) >> 16;
    return (ushort_t)r;
}

// ---------------------------------------------------------------------------
// Convert x (fp32) -> g_xb (bf16). 8 elems/thread. grid 4096 x 256.
// ---------------------------------------------------------------------------
__global__ __launch_bounds__(256) void cvt_x(const float* __restrict__ x)
{
    size_t i = ((size_t)blockIdx.x * 256 + threadIdx.x) * 8;
    float4 a = *(const float4*)(x + i);
    float4 b = *(const float4*)(x + i + 4);
    ushort_t r[8];
    r[0] = f2bf(a.x); r[1] = f2bf(a.y); r[2] = f2bf(a.z); r[3] = f2bf(a.w);
    r[4] = f2bf(b.x); r[5] = f2bf(b.y); r[6] = f2bf(b.z); r[7] = f2bf(b.w);
    *(uint4*)(g_xb + i) = *(const uint4*)r;
}

// ---------------------------------------------------------------------------
// Prepack Wx^T (fp32 1024x4096 -> bf16 [j][1024]). grid (16,64) x 256.
// ---------------------------------------------------------------------------
__global__ __launch_bounds__(256) void prepack_wx(const float* __restrict__ Wx)
{
    __shared__ ushort_t tile[64][66];
    int k0 = blockIdx.x * 64, j0 = blockIdx.y * 64;
    int c = threadIdx.x & 63, r4 = threadIdx.x >> 6;
    for (int rr = 0; rr < 64; rr += 4) {
        int r = rr + r4;
        tile[r][c] = f2bf(Wx[(size_t)(k0 + r) * 4096 + j0 + c]);
    }
    __syncthreads();
    for (int rr = 0; rr < 64; rr += 4) {
        int j = rr + r4;
        g_Wxt[(size_t)(j0 + j) * 1024 + k0 + c] = tile[c][j];
    }
}

// ---------------------------------------------------------------------------
// Prepack [Wh^T | Wattn^T] (-> bf16 [j][2048]). grid (32,64) x 256.
// ---------------------------------------------------------------------------
__global__ __launch_bounds__(256) void prepack_w2(
    const float* __restrict__ Wh, const float* __restrict__ Wattn)
{
    __shared__ ushort_t tile[64][66];
    int k0 = blockIdx.x * 64, j0 = blockIdx.y * 64;
    const float* src = (k0 < 1024) ? Wh : Wattn;
    int krel = (k0 < 1024) ? k0 : k0 - 1024;
    int c = threadIdx.x & 63, r4 = threadIdx.x >> 6;
    for (int rr = 0; rr < 64; rr += 4) {
        int r = rr + r4;
        tile[r][c] = f2bf(src[(size_t)(krel + r) * 4096 + j0 + c]);
    }
    __syncthreads();
    for (int rr = 0; rr < 64; rr += 4) {
        int j = rr + r4;
        g_W2[(size_t)(j0 + j) * 2048 + k0 + c] = tile[c][j];
    }
}

// ---------------------------------------------------------------------------
// Init: h0 = c0 = mean over 16 spatial of A (fp32). grid 1024 x 256.
// ---------------------------------------------------------------------------
__global__ __launch_bounds__(256) void init_hc(const float* __restrict__ A)
{
    int gid = blockIdx.x * 256 + threadIdx.x;       // (n,h)
    int n = gid >> 10, h = gid & 1023;
    const float* ap = A + ((size_t)gid << 4);
    float4 a0 = *(const float4*)(ap);
    float4 a1 = *(const float4*)(ap + 4);
    float4 a2 = *(const float4*)(ap + 8);
    float4 a3 = *(const float4*)(ap + 12);
    float s = (a0.x+a0.y+a0.z+a0.w) + (a1.x+a1.y+a1.z+a1.w)
            + (a2.x+a2.y+a2.z+a2.w) + (a3.x+a3.y+a3.z+a3.w);
    s *= (1.0f / 16.0f);
    g_Hc[0][n * 2048 + h] = f2bf(s);
    g_c[gid] = s;
}

// ---------------------------------------------------------------------------
// Hoisted GEMM: g_px[t][n][j] = x@Wx + b.  M=8192 (n*32+t), N=4096, K=1024.
// 128x128 tiles, grid 2048 (2 blocks/CU), 256 thr, 4 waves, 4x4 acc/wave.
// ---------------------------------------------------------------------------
#define PADX 72
__global__ __launch_bounds__(256) void xw_gemm(const float* __restrict__ bias)
{
    __shared__ __align__(16) ushort_t lA[128 * PADX];
    __shared__ __align__(16) ushort_t lB[128 * PADX];
    int b = blockIdx.x;
    int mb = b >> 5, jb = b & 31;
    int m0 = mb * 128, j0 = jb * 128;
    int tid = threadIdx.x;
    int row = tid >> 1, half = tid & 1;
    const ushort_t* ga = g_xb  + (size_t)(m0 + row) * 1024 + half * 32;
    const ushort_t* gb = g_Wxt + (size_t)(j0 + row) * 1024 + half * 32;
    ushort_t* wA = lA + row * PADX + half * 32;
    ushort_t* wB = lB + row * PADX + half * 32;

    int lane = tid & 63, wv = tid >> 6;
    int wm = wv >> 1, wn = wv & 1;
    int lm = lane & 15, quad = lane >> 4;

    uint4 ra[4], rb[4];
    #pragma unroll
    for (int q = 0; q < 4; ++q) { ra[q] = ((const uint4*)ga)[q]; rb[q] = ((const uint4*)gb)[q]; }

    floatx4 acc[4][4] = {};
    for (int it = 0; it < 16; ++it) {
        __syncthreads();
        #pragma unroll
        for (int q = 0; q < 4; ++q) { ((uint4*)wA)[q] = ra[q]; ((uint4*)wB)[q] = rb[q]; }
        __syncthreads();
        int nxt = (it < 15) ? (it + 1) * 64 : 0;
        #pragma unroll
        for (int q = 0; q < 4; ++q) {
            ra[q] = ((const uint4*)(ga + nxt))[q];
            rb[q] = ((const uint4*)(gb + nxt))[q];
        }
        #pragma unroll
        for (int ks = 0; ks < 2; ++ks) {
            short8 af[4], bf[4];
            #pragma unroll
            for (int i = 0; i < 4; ++i)
                af[i] = *(const short8*)(lA + (wm*64 + i*16 + lm) * PADX + ks*32 + quad*8);
            #pragma unroll
            for (int j = 0; j < 4; ++j)
                bf[j] = *(const short8*)(lB + (wn*64 + j*16 + lm) * PADX + ks*32 + quad*8);
            #pragma unroll
            for (int i = 0; i < 4; ++i)
                #pragma unroll
                for (int j = 0; j < 4; ++j)
                    acc[i][j] = __builtin_amdgcn_mfma_f32_16x16x32_bf16(af[i], bf[j], acc[i][j], 0, 0, 0);
        }
    }
    #pragma unroll
    for (int i = 0; i < 4; ++i) {
        #pragma unroll
        for (int q = 0; q < 4; ++q) {
            int rl = wm*64 + i*16 + quad*4 + q;
            int rg = m0 + rl;
            int nn = rg >> 5, tt = rg & 31;
            float* dst = g_px + ((size_t)tt * 256 + nn) * 4096 + j0;
            #pragma unroll
            for (int j = 0; j < 4; ++j) {
                int cl = wn*64 + j*16 + lm;
                dst[cl] = acc[i][j][q] + bias[j0 + cl];
            }
        }
    }
}

// ---------------------------------------------------------------------------
// Attention step: reads h-section of Hc[t&1], writes its attn-section.
// grid 256 (block per n) x 256 (4 h per thread).
// ---------------------------------------------------------------------------
__global__ __launch_bounds__(256) void attn_step(const float* __restrict__ A, int t)
{
    ushort_t* Hc = g_Hc[t & 1];
    int n = blockIdx.x, tid = threadIdx.x;
    const ushort_t* hp = Hc + n * 2048;
    const float* ap = A + ((size_t)n << 14);        // n*1024*16
    int hbase = tid * 4;

    float sp[16];
    #pragma unroll
    for (int l = 0; l < 16; ++l) sp[l] = 0.f;
    float av[4][16];
    #pragma unroll
    for (int i = 0; i < 4; ++i) {
        const float* ar = ap + ((size_t)(hbase + i) << 4);
        float4 b0 = *(const float4*)(ar);
        float4 b1 = *(const float4*)(ar + 4);
        float4 b2 = *(const float4*)(ar + 8);
        float4 b3 = *(const float4*)(ar + 12);
        av[i][0]=b0.x; av[i][1]=b0.y; av[i][2]=b0.z; av[i][3]=b0.w;
        av[i][4]=b1.x; av[i][5]=b1.y; av[i][6]=b1.z; av[i][7]=b1.w;
        av[i][8]=b2.x; av[i][9]=b2.y; av[i][10]=b2.z; av[i][11]=b2.w;
        av[i][12]=b3.x; av[i][13]=b3.y; av[i][14]=b3.z; av[i][15]=b3.w;
    }
    float hv[4];
    #pragma unroll
    for (int i = 0; i < 4; ++i) hv[i] = bf2f(hp[hbase + i]);
    #pragma unroll
    for (int i = 0; i < 4; ++i)
        #pragma unroll
        for (int l = 0; l < 16; ++l) sp[l] += hv[i] * av[i][l];

    #pragma unroll
    for (int l = 0; l < 16; ++l) {
        float v = sp[l];
        v += __shfl_xor(v, 32); v += __shfl_xor(v, 16); v += __shfl_xor(v, 8);
        v += __shfl_xor(v, 4);  v += __shfl_xor(v, 2);  v += __shfl_xor(v, 1);
        sp[l] = v;
    }
    __shared__ float red[4][16];
    int wv = tid >> 6, lane = tid & 63;
    if (lane == 0) {
        #pragma unroll
        for (int l = 0; l < 16; ++l) red[wv][l] = sp[l];
    }
    __syncthreads();
    float w[16], mx = -1e30f;
    #pragma unroll
    for (int l = 0; l < 16; ++l) {
        float s = (red[0][l] + red[1][l] + red[2][l] + red[3][l]) * 0.03125f;
        w[l] = s; mx = fmaxf(mx, s);
    }
    float sum = 0.f;
    #pragma unroll
    for (int l = 0; l < 16; ++l) { w[l] = __expf(w[l] - mx); sum += w[l]; }
    float inv = 1.f / sum;
    #pragma unroll
    for (int i = 0; i < 4; ++i) {
        float acc = 0.f;
        #pragma unroll
        for (int l = 0; l < 16; ++l) acc += av[i][l] * (w[l] * inv);
        Hc[n * 2048 + 1024 + hbase + i] = f2bf(acc);
    }
}

// ---------------------------------------------------------------------------
// Per-step GEMM (256x4096, K=2048 = [h|attn] @ [Wh;Wattn]) + px + LSTM.
// 256 blocks (XCD-swizzled), 512 thr = 8 waves (2/SIMD).
// 64x64 tile; 8-way K-split across waves, 4x4 acc each; lP atomic reduce.
// Gate-grouped B columns: block's j-rows = { g*1024 + hh0 + 0..15, g=0..3 }.
// ---------------------------------------------------------------------------
#define PADS 264
__global__ __launch_bounds__(512) void step_gemm(float* __restrict__ out, int t)
{
    __shared__ __align__(16) ushort_t lA[64 * PADS];
    __shared__ __align__(16) ushort_t lB[64 * PADS];
    __shared__ float lP[64 * 65];

    const ushort_t* Hin  = g_Hc[t & 1];
    ushort_t*       Hout = g_Hc[(t + 1) & 1];

    int b = blockIdx.x;
    int xcd = b & 7, r = b >> 3;
    int mt_ = r & 3, jt = xcd * 8 + (r >> 2);
    int n0 = mt_ * 64, hh0 = jt * 16;
    int tid = threadIdx.x;

    // staging: thread = (mrow, cg); covers 64 B = chunks cg*4 .. cg*4+3
    int mrow = tid >> 3, cg = tid & 7;
    const ushort_t* ga = Hin + (size_t)(n0 + mrow) * 2048 + cg * 32;
    int jg = ((mrow >> 4) << 10) + hh0 + (mrow & 15);      // gate-grouped j
    const ushort_t* gb = g_W2 + (size_t)jg * 2048 + cg * 32;
    ushort_t* wA = lA + mrow * PADS + cg * 32;
    ushort_t* wB = lB + mrow * PADS + cg * 32;

    for (int i = tid; i < 64 * 65; i += 512) lP[i] = 0.f;

    int lane = tid & 63, wv = tid >> 6;
    int lm = lane & 15, quad = lane >> 4;
    int kbase = wv * 32 + quad * 8;        // wave wv owns kstep wv of each chunk

    uint4 ra[4], rb[4];
    #pragma unroll
    for (int q = 0; q < 4; ++q) { ra[q] = ((const uint4*)ga)[q]; rb[q] = ((const uint4*)gb)[q]; }

    floatx4 acc[4][4] = {};
    for (int it = 0; it < 8; ++it) {
        __syncthreads();
        #pragma unroll
        for (int q = 0; q < 4; ++q) { ((uint4*)wA)[q] = ra[q]; ((uint4*)wB)[q] = rb[q]; }
        __syncthreads();
        int nxt = (it < 7) ? (it + 1) * 256 : 0;
        #pragma unroll
        for (int q = 0; q < 4; ++q) {
            ra[q] = ((const uint4*)(ga + nxt))[q];
            rb[q] = ((const uint4*)(gb + nxt))[q];
        }
        short8 af[4], bf[4];
        #pragma unroll
        for (int i = 0; i < 4; ++i)
            af[i] = *(const short8*)(lA + (i*16 + lm) * PADS + kbase);
        #pragma unroll
        for (int j = 0; j < 4; ++j)
            bf[j] = *(const short8*)(lB + (j*16 + lm) * PADS + kbase);
        #pragma unroll
        for (int i = 0; i < 4; ++i)
            #pragma unroll
            for (int j = 0; j < 4; ++j)
                acc[i][j] = __builtin_amdgcn_mfma_f32_16x16x32_bf16(af[i], bf[j], acc[i][j], 0, 0, 0);
    }

    // combine 8 waves' K-partials
    #pragma unroll
    for (int i = 0; i < 4; ++i)
        #pragma unroll
        for (int j = 0; j < 4; ++j)
            #pragma unroll
            for (int q = 0; q < 4; ++q)
                atomicAdd(&lP[(i*16 + quad*4 + q) * 65 + j*16 + lm], acc[i][j][q]);
    __syncthreads();

    // LSTM pointwise (preact = lP + g_px)
    #pragma unroll
    for (int q = 0; q < 2; ++q) {
        int idx = tid + q * 512;           // 0..1023 = (nl, hl)
        int nl = idx >> 4, hl = idx & 15;
        const float* px = g_px + ((size_t)t * 256 + (n0 + nl)) * 4096 + hh0 + hl;
        float ai  = lP[nl*65 +      hl] + px[0];
        float afv = lP[nl*65 + 16 + hl] + px[1024];
        float ao  = lP[nl*65 + 32 + hl] + px[2048];
        float ag  = lP[nl*65 + 48 + hl] + px[3072];
        float iv = 1.f / (1.f + __expf(-ai));
        float fv = 1.f / (1.f + __expf(-afv));
        float ov = 1.f / (1.f + __expf(-ao));
        float gv = tanhf(ag);
        int ng = n0 + nl, hg = hh0 + hl;
        float cold = g_c[ng * 1024 + hg];
        float cnew = fv * cold + iv * gv;
        float hnew = ov * tanhf(cnew);
        g_c[ng * 1024 + hg] = cnew;
        Hout[ng * 2048 + hg] = f2bf(hnew);
        out[(size_t)ng * (T_SEQ * HH) + (size_t)t * HH + hg] = hnew;
    }
}

// ---------------------------------------------------------------------------
extern "C" void kernel_launch(void* const* d_in, const int* in_sizes, int n_in,
                              void* d_out, int out_size, void* d_ws, size_t ws_size,
                              hipStream_t stream) {
    const float* x     = (const float*)d_in[0];
    const float* A     = (const float*)d_in[1];
    const float* Wx    = (const float*)d_in[2];
    const float* Wh    = (const float*)d_in[3];
    const float* Wattn = (const float*)d_in[4];
    const float* bias  = (const float*)d_in[5];
    float* out = (float*)d_out;

    cvt_x<<<4096, 256, 0, stream>>>(x);
    prepack_wx<<<dim3(16, 64), 256, 0, stream>>>(Wx);
    prepack_w2<<<dim3(32, 64), 256, 0, stream>>>(Wh, Wattn);
    init_hc<<<1024, 256, 0, stream>>>(A);
    xw_gemm<<<2048, 256, 0, stream>>>(bias);
    for (int t = 0; t < T_SEQ; ++t) {
        attn_step<<<256, 256, 0, stream>>>(A, t);
        step_gemm<<<256, 512, 0, stream>>>(out, t);
    }
}

// Round 4
// 2016.984 us; speedup vs baseline: 1.6917x; 1.6917x over previous
//
#include <hip/hip_runtime.h>

#define N_B 256
#define T_SEQ 32
#define DD 1024
#define HH 1024

typedef short short8 __attribute__((ext_vector_type(8)));
typedef float floatx4 __attribute__((ext_vector_type(4)));
typedef unsigned short ushort_t;

// ---- scratch as device globals (no dependence on ws_size) ------------------
__device__ __align__(16) ushort_t g_Wxt[(size_t)4096 * 1024];      // 8 MB  [j][k]=Wx^T
__device__ __align__(16) ushort_t g_W2 [(size_t)4096 * 2048];      // 16 MB [j][k]=[Wh^T|Wattn^T]
__device__ __align__(16) ushort_t g_xb [(size_t)8192 * 1024];      // 16 MB bf16 x, row = t*256+n
__device__ __align__(16) float    g_px [(size_t)8192 * 4096];      // 134 MB fp32, row = t*256+n
__device__ __align__(16) ushort_t g_Ab [(size_t)N_B * 16384];      // 8 MB bf16 A [n][h][l]
__device__ __align__(16) ushort_t g_At [(size_t)N_B * 16384];      // 8 MB bf16 A [n][l][h]
__device__ __align__(16) ushort_t g_Hc[2][N_B * 2048];             // [h|attn] bf16 ping-pong
__device__ __align__(16) float    g_c [N_B * HH];                  // fp32 cell state

__device__ __forceinline__ float bf2f(ushort_t u){
    union { unsigned int i; float f; } v; v.i = ((unsigned int)u) << 16; return v.f;
}
__device__ __forceinline__ ushort_t f2bf(float f){
    union { unsigned int i; float f; } v; v.f = f;
    unsigned int i = v.i;
    unsigned int r = (i + 0x7FFFu + ((i >> 16) & 1u)) >> 16;
    return (ushort_t)r;
}
// async global->LDS, 16B per lane; lds dest = wave-uniform base + lane*16
__device__ __forceinline__ void gload16(const ushort_t* g, ushort_t* l) {
    __builtin_amdgcn_global_load_lds((const __attribute__((address_space(1))) void*)g,
                                     (__attribute__((address_space(3))) void*)l, 16, 0, 0);
}
__device__ __forceinline__ void unp8(uint4 u, float* f) {
    const ushort_t* s = (const ushort_t*)&u;
    #pragma unroll
    for (int i = 0; i < 8; ++i) f[i] = bf2f(s[i]);
}

// ---------------------------------------------------------------------------
// x (fp32 [n][t][d]) -> g_xb (bf16, row t*256+n). grid 8192 x 128.
// ---------------------------------------------------------------------------
__global__ __launch_bounds__(128) void cvt_x(const float* __restrict__ x)
{
    int b = blockIdx.x;                 // in-row = n*32 + t
    int n = b >> 5, tt = b & 31;
    int tid = threadIdx.x;
    const float* src = x + (size_t)b * 1024 + tid * 8;
    float4 a = *(const float4*)src;
    float4 c = *(const float4*)(src + 4);
    ushort_t r[8];
    r[0]=f2bf(a.x); r[1]=f2bf(a.y); r[2]=f2bf(a.z); r[3]=f2bf(a.w);
    r[4]=f2bf(c.x); r[5]=f2bf(c.y); r[6]=f2bf(c.z); r[7]=f2bf(c.w);
    *(uint4*)(g_xb + (size_t)(tt * 256 + n) * 1024 + tid * 8) = *(const uint4*)r;
}

// ---------------------------------------------------------------------------
// A fp32 [n][h][l] -> g_Ab bf16 (same layout) + g_At bf16 [n][l][h].
// grid 256 (block per n) x 256 (4 h per thread).
// ---------------------------------------------------------------------------
__global__ __launch_bounds__(256) void cvt_a(const float* __restrict__ A)
{
    int n = blockIdx.x, tid = threadIdx.x;
    int h0 = tid * 4;
    const float* ap = A + (size_t)n * 16384;
    ushort_t tmp[4][16];
    #pragma unroll
    for (int i = 0; i < 4; ++i) {
        const float* row = ap + (size_t)(h0 + i) * 16;
        #pragma unroll
        for (int l = 0; l < 16; ++l) tmp[i][l] = f2bf(row[l]);
        ushort_t* dst = g_Ab + (size_t)n * 16384 + (size_t)(h0 + i) * 16;
        *(uint4*)dst       = *(const uint4*)&tmp[i][0];
        *(uint4*)(dst + 8) = *(const uint4*)&tmp[i][8];
    }
    #pragma unroll
    for (int l = 0; l < 16; ++l) {
        ushort_t pk[4] = { tmp[0][l], tmp[1][l], tmp[2][l], tmp[3][l] };
        *(uint2*)(g_At + (size_t)n * 16384 + (size_t)l * 1024 + h0) = *(const uint2*)pk;
    }
}

// ---------------------------------------------------------------------------
// Prepack Wx^T. grid (16,64) x 256.
// ---------------------------------------------------------------------------
__global__ __launch_bounds__(256) void prepack_wx(const float* __restrict__ Wx)
{
    __shared__ ushort_t tile[64][66];
    int k0 = blockIdx.x * 64, j0 = blockIdx.y * 64;
    int c = threadIdx.x & 63, r4 = threadIdx.x >> 6;
    for (int rr = 0; rr < 64; rr += 4) {
        int r = rr + r4;
        tile[r][c] = f2bf(Wx[(size_t)(k0 + r) * 4096 + j0 + c]);
    }
    __syncthreads();
    for (int rr = 0; rr < 64; rr += 4) {
        int j = rr + r4;
        g_Wxt[(size_t)(j0 + j) * 1024 + k0 + c] = tile[c][j];
    }
}

// ---------------------------------------------------------------------------
// Prepack [Wh^T | Wattn^T]. grid (32,64) x 256.
// ---------------------------------------------------------------------------
__global__ __launch_bounds__(256) void prepack_w2(
    const float* __restrict__ Wh, const float* __restrict__ Wattn)
{
    __shared__ ushort_t tile[64][66];
    int k0 = blockIdx.x * 64, j0 = blockIdx.y * 64;
    const float* src = (k0 < 1024) ? Wh : Wattn;
    int krel = (k0 < 1024) ? k0 : k0 - 1024;
    int c = threadIdx.x & 63, r4 = threadIdx.x >> 6;
    for (int rr = 0; rr < 64; rr += 4) {
        int r = rr + r4;
        tile[r][c] = f2bf(src[(size_t)(krel + r) * 4096 + j0 + c]);
    }
    __syncthreads();
    for (int rr = 0; rr < 64; rr += 4) {
        int j = rr + r4;
        g_W2[(size_t)(j0 + j) * 2048 + k0 + c] = tile[c][j];
    }
}

// ---------------------------------------------------------------------------
// Init: h0 = c0 = mean over 16 spatial of A. grid 1024 x 256.
// ---------------------------------------------------------------------------
__global__ __launch_bounds__(256) void init_hc(const float* __restrict__ A)
{
    int gid = blockIdx.x * 256 + threadIdx.x;       // (n,h)
    int n = gid >> 10, h = gid & 1023;
    const float* ap = A + ((size_t)gid << 4);
    float4 a0 = *(const float4*)(ap);
    float4 a1 = *(const float4*)(ap + 4);
    float4 a2 = *(const float4*)(ap + 8);
    float4 a3 = *(const float4*)(ap + 12);
    float s = (a0.x+a0.y+a0.z+a0.w) + (a1.x+a1.y+a1.z+a1.w)
            + (a2.x+a2.y+a2.z+a2.w) + (a3.x+a3.y+a3.z+a3.w);
    s *= (1.0f / 16.0f);
    g_Hc[0][n * 2048 + h] = f2bf(s);
    g_c[gid] = s;
}

// ---------------------------------------------------------------------------
// Hoisted GEMM: g_px[t*256+n][j] = x@Wx + b. M=8192, N=4096, K=1024.
// m97 recipe: 128x128 tile, BK=64, global_load_lds(16B), 4x4 acc/wave.
// Epilogue: LDS transpose -> dense float4 stores (kills write-amp).
// ---------------------------------------------------------------------------
__global__ __launch_bounds__(256) void xw_gemm(const float* __restrict__ bias)
{
    __shared__ __align__(16) char smem[33280];
    ushort_t* lA = (ushort_t*)smem;                 // 128 x 64 bf16 (16 KB)
    ushort_t* lB = (ushort_t*)(smem + 16384);       // 128 x 64 bf16 (16 KB)
    float*    lP = (float*)smem;                    // 64 x 130 fp32 (epilogue alias)

    int b = blockIdx.x;
    int mb = b >> 5, jb = b & 31;
    int m0 = mb * 128, j0 = jb * 128;
    int tid = threadIdx.x, lane = tid & 63, wv = tid >> 6;
    int wm = wv >> 1, wn = wv & 1;
    int lm = lane & 15, quad = lane >> 4;

    // staging: per glds instr, 64 lanes = 8 rows x 8 segs(16B)
    int srow = lane >> 3, sseg = lane & 7;
    const ushort_t* gA = g_xb  + (size_t)(m0 + wv * 32 + srow) * 1024 + sseg * 8;
    const ushort_t* gB = g_Wxt + (size_t)(j0 + wv * 32 + srow) * 1024 + sseg * 8;

    floatx4 acc[4][4] = {};
    for (int kt = 0; kt < 16; ++kt) {
        __syncthreads();                            // prev compute done
        #pragma unroll
        for (int i = 0; i < 4; ++i) {
            gload16(gA + (size_t)i * 8 * 1024 + kt * 64, lA + (wv * 32 + i * 8) * 64);
            gload16(gB + (size_t)i * 8 * 1024 + kt * 64, lB + (wv * 32 + i * 8) * 64);
        }
        __syncthreads();                            // vmcnt drained: tile ready
        #pragma unroll
        for (int ks = 0; ks < 2; ++ks) {
            short8 af[4], bf[4];
            #pragma unroll
            for (int i = 0; i < 4; ++i)
                af[i] = *(const short8*)(lA + (wm*64 + i*16 + lm) * 64 + ks*32 + quad*8);
            #pragma unroll
            for (int j = 0; j < 4; ++j)
                bf[j] = *(const short8*)(lB + (wn*64 + j*16 + lm) * 64 + ks*32 + quad*8);
            #pragma unroll
            for (int i = 0; i < 4; ++i)
                #pragma unroll
                for (int j = 0; j < 4; ++j)
                    acc[i][j] = __builtin_amdgcn_mfma_f32_16x16x32_bf16(af[i], bf[j], acc[i][j], 0, 0, 0);
        }
    }

    // epilogue: 2 phases of 64 rows; LDS-transpose then dense float4 stores
    #pragma unroll
    for (int ph = 0; ph < 2; ++ph) {
        __syncthreads();
        if (wm == ph) {
            #pragma unroll
            for (int i = 0; i < 4; ++i)
                #pragma unroll
                for (int j = 0; j < 4; ++j)
                    #pragma unroll
                    for (int q = 0; q < 4; ++q)
                        lP[(i*16 + quad*4 + q) * 130 + wn*64 + j*16 + lm] = acc[i][j][q];
        }
        __syncthreads();
        int row = tid >> 2, seg = tid & 3;
        const float* src = lP + row * 130 + seg * 32;
        float* dst = g_px + (size_t)(m0 + ph * 64 + row) * 4096 + j0 + seg * 32;
        const float* bb = bias + j0 + seg * 32;
        #pragma unroll
        for (int i = 0; i < 8; ++i) {
            float4 v = *(const float4*)(src + i * 4);
            float4 w = *(const float4*)(bb + i * 4);
            v.x += w.x; v.y += w.y; v.z += w.z; v.w += w.w;
            *(float4*)(dst + i * 4) = v;
        }
    }
}

// ---------------------------------------------------------------------------
// Attention step: logits from g_At (coalesced in h), softmax, weighted sum
// from g_Ab. grid 256 (block per n) x 256.
// ---------------------------------------------------------------------------
__global__ __launch_bounds__(256) void attn_step(int t)
{
    ushort_t* Hc = g_Hc[t & 1];
    int n = blockIdx.x, tid = threadIdx.x;
    int lane = tid & 63, wv = tid >> 6;
    const ushort_t* hp = Hc + n * 2048;

    // this lane's 16-wide h-chunk of h_t
    int hc = lane * 16;
    float hv[16];
    unp8(*(const uint4*)(hp + hc), hv);
    unp8(*(const uint4*)(hp + hc + 8), hv + 8);

    __shared__ float red[16];
    float lg[4];
    #pragma unroll
    for (int l4 = 0; l4 < 4; ++l4) {
        int l = wv * 4 + l4;
        const ushort_t* ar = g_At + (size_t)n * 16384 + (size_t)l * 1024 + hc;
        float av[16];
        unp8(*(const uint4*)ar, av);
        unp8(*(const uint4*)(ar + 8), av + 8);
        float s = 0.f;
        #pragma unroll
        for (int i = 0; i < 16; ++i) s += hv[i] * av[i];
        s += __shfl_xor(s, 32); s += __shfl_xor(s, 16); s += __shfl_xor(s, 8);
        s += __shfl_xor(s, 4);  s += __shfl_xor(s, 2);  s += __shfl_xor(s, 1);
        lg[l4] = s;
    }
    if (lane == 0) {
        #pragma unroll
        for (int l4 = 0; l4 < 4; ++l4) red[wv * 4 + l4] = lg[l4];
    }
    __syncthreads();
    float w[16], mx = -1e30f;
    #pragma unroll
    for (int l = 0; l < 16; ++l) {
        float s = red[l] * 0.03125f;
        w[l] = s; mx = fmaxf(mx, s);
    }
    float sum = 0.f;
    #pragma unroll
    for (int l = 0; l < 16; ++l) { w[l] = __expf(w[l] - mx); sum += w[l]; }
    float inv = 1.f / sum;
    #pragma unroll
    for (int l = 0; l < 16; ++l) w[l] *= inv;

    // weighted sum: thread covers 4 h rows of g_Ab
    int h0 = tid * 4;
    const ushort_t* ab = g_Ab + (size_t)n * 16384 + (size_t)h0 * 16;
    ushort_t outp[4];
    #pragma unroll
    for (int i = 0; i < 4; ++i) {
        float av[16];
        unp8(*(const uint4*)(ab + i * 16), av);
        unp8(*(const uint4*)(ab + i * 16 + 8), av + 8);
        float acc = 0.f;
        #pragma unroll
        for (int l = 0; l < 16; ++l) acc += av[l] * w[l];
        outp[i] = f2bf(acc);
    }
    *(uint2*)(Hc + n * 2048 + 1024 + h0) = *(const uint2*)outp;
}

// ---------------------------------------------------------------------------
// Per-step GEMM: C[256x4096] = [h|attn] @ [Wh;Wattn] (K=2048) + px + LSTM.
// 256 blocks (XCD-pinned j-strips), 4 waves. 64x64 tile, BK=128,
// double-buffered global_load_lds; each wave owns a k-quarter of the staged
// tile with a full 64x64 4x4 accumulator; LDS-atomic reduce across waves.
// Gate-grouped B rows: j = gate*1024 + hh0 + (0..15).
// ---------------------------------------------------------------------------
__global__ __launch_bounds__(256) void step_gemm(float* __restrict__ out, int t)
{
    __shared__ __align__(16) ushort_t lA[2][64 * 128];
    __shared__ __align__(16) ushort_t lB[2][64 * 128];
    __shared__ float lP[64 * 65];

    const ushort_t* Hin  = g_Hc[t & 1];
    ushort_t*       Hout = g_Hc[(t + 1) & 1];

    int b = blockIdx.x;
    int xcd = b & 7, r = b >> 3;
    int mt_ = r & 3, jt = xcd * 8 + (r >> 2);
    int n0 = mt_ * 64, hh0 = jt * 16;
    int tid = threadIdx.x, lane = tid & 63, wv = tid >> 6;
    int lm = lane & 15, quad = lane >> 4;

    for (int i = tid; i < 64 * 65; i += 256) lP[i] = 0.f;

    // staging: per glds instr, 64 lanes = 4 rows x 16 segs(16B). Wave wv
    // stages rows [wv*16, wv*16+16) of both tiles (A: n-rows, B: gate wv).
    int srow = lane >> 4, sseg = lane & 15;
    const ushort_t* gA = Hin + (size_t)(n0 + wv * 16 + srow) * 2048 + sseg * 8;
    const ushort_t* gB = g_W2 + (size_t)(wv * 1024 + hh0 + srow) * 2048 + sseg * 8;
    // B row jrow = wv*16 + i*4 + srow -> jg = wv*1024 + hh0 + (i*4 + srow)

    floatx4 acc[4][4] = {};
    int ko = wv * 32 + quad * 8;       // this wave's k-quarter of the tile

    // prologue
    #pragma unroll
    for (int i = 0; i < 4; ++i) {
        gload16(gA + (size_t)i * 4 * 2048, &lA[0][(wv * 16 + i * 4) * 128]);
        gload16(gB + (size_t)i * 4 * 2048, &lB[0][(wv * 16 + i * 4) * 128]);
    }
    __syncthreads();

    for (int it = 0; it < 16; ++it) {
        if (it < 15) {
            int p = (it + 1) & 1, kk = (it + 1) * 128;
            #pragma unroll
            for (int i = 0; i < 4; ++i) {
                gload16(gA + (size_t)i * 4 * 2048 + kk, &lA[p][(wv * 16 + i * 4) * 128]);
                gload16(gB + (size_t)i * 4 * 2048 + kk, &lB[p][(wv * 16 + i * 4) * 128]);
            }
        }
        int p = it & 1;
        short8 af[4], bf[4];
        #pragma unroll
        for (int i = 0; i < 4; ++i)
            af[i] = *(const short8*)(&lA[p][(i * 16 + lm) * 128 + ko]);
        #pragma unroll
        for (int j = 0; j < 4; ++j)
            bf[j] = *(const short8*)(&lB[p][(j * 16 + lm) * 128 + ko]);
        #pragma unroll
        for (int i = 0; i < 4; ++i)
            #pragma unroll
            for (int j = 0; j < 4; ++j)
                acc[i][j] = __builtin_amdgcn_mfma_f32_16x16x32_bf16(af[i], bf[j], acc[i][j], 0, 0, 0);
        __syncthreads();   // drains prefetch (overlapped compute) + ds reads
    }

    // reduce 4 waves' k-partials
    #pragma unroll
    for (int i = 0; i < 4; ++i)
        #pragma unroll
        for (int j = 0; j < 4; ++j)
            #pragma unroll
            for (int q = 0; q < 4; ++q)
                atomicAdd(&lP[(i * 16 + quad * 4 + q) * 65 + j * 16 + lm], acc[i][j][q]);
    __syncthreads();

    // LSTM pointwise (preact = lP + g_px)
    #pragma unroll
    for (int q = 0; q < 4; ++q) {
        int idx = tid + q * 256;           // (nl, hl)
        int nl = idx >> 4, hl = idx & 15;
        const float* px = g_px + ((size_t)t * 256 + (n0 + nl)) * 4096 + hh0 + hl;
        float ai  = lP[nl * 65 +      hl] + px[0];
        float afv = lP[nl * 65 + 16 + hl] + px[1024];
        float ao  = lP[nl * 65 + 32 + hl] + px[2048];
        float ag  = lP[nl * 65 + 48 + hl] + px[3072];
        float iv = 1.f / (1.f + __expf(-ai));
        float fv = 1.f / (1.f + __expf(-afv));
        float ov = 1.f / (1.f + __expf(-ao));
        float gv = tanhf(ag);
        int ng = n0 + nl, hg = hh0 + hl;
        float cold = g_c[ng * 1024 + hg];
        float cnew = fv * cold + iv * gv;
        float hnew = ov * tanhf(cnew);
        g_c[ng * 1024 + hg] = cnew;
        Hout[ng * 2048 + hg] = f2bf(hnew);
        out[(size_t)ng * (T_SEQ * HH) + (size_t)t * HH + hg] = hnew;
    }
}

// ---------------------------------------------------------------------------
extern "C" void kernel_launch(void* const* d_in, const int* in_sizes, int n_in,
                              void* d_out, int out_size, void* d_ws, size_t ws_size,
                              hipStream_t stream) {
    const float* x     = (const float*)d_in[0];
    const float* A     = (const float*)d_in[1];
    const float* Wx    = (const float*)d_in[2];
    const float* Wh    = (const float*)d_in[3];
    const float* Wattn = (const float*)d_in[4];
    const float* bias  = (const float*)d_in[5];
    float* out = (float*)d_out;

    cvt_x<<<8192, 128, 0, stream>>>(x);
    cvt_a<<<256, 256, 0, stream>>>(A);
    prepack_wx<<<dim3(16, 64), 256, 0, stream>>>(Wx);
    prepack_w2<<<dim3(32, 64), 256, 0, stream>>>(Wh, Wattn);
    init_hc<<<1024, 256, 0, stream>>>(A);
    xw_gemm<<<2048, 256, 0, stream>>>(bias);
    for (int t = 0; t < T_SEQ; ++t) {
        attn_step<<<256, 256, 0, stream>>>(t);
        step_gemm<<<256, 256, 0, stream>>>(out, t);
    }
}

// Round 5
// 1832.276 us; speedup vs baseline: 1.8622x; 1.1008x over previous
//
#include <hip/hip_runtime.h>

#define N_B 256
#define T_SEQ 32
#define DD 1024
#define HH 1024

typedef short short8 __attribute__((ext_vector_type(8)));
typedef float floatx4 __attribute__((ext_vector_type(4)));
typedef unsigned short ushort_t;

// ---- scratch as device globals (no dependence on ws_size) ------------------
__device__ __align__(16) ushort_t g_Wxt[(size_t)4096 * 1024];      // 8 MB  [j][k]=Wx^T
__device__ __align__(16) ushort_t g_W2 [(size_t)4096 * 2048];      // 16 MB [j][k]=[Wh^T|Wattn^T]
__device__ __align__(16) ushort_t g_xb [(size_t)8192 * 1024];      // 16 MB bf16 x, row = t*256+n
__device__ __align__(16) float    g_px [(size_t)8192 * 4096];      // 134 MB fp32, row = t*256+n
__device__ __align__(16) ushort_t g_Ab [(size_t)N_B * 16384];      // 8 MB bf16 A [n][h][l]
__device__ __align__(16) ushort_t g_At [(size_t)N_B * 16384];      // 8 MB bf16 A [n][l][h]
__device__ __align__(16) ushort_t g_Hc[2][N_B * 2048];             // [h|attn] bf16 ping-pong
__device__ __align__(16) float    g_c [N_B * HH];                  // fp32 cell state

__device__ __forceinline__ float bf2f(ushort_t u){
    union { unsigned int i; float f; } v; v.i = ((unsigned int)u) << 16; return v.f;
}
__device__ __forceinline__ ushort_t f2bf(float f){
    union { unsigned int i; float f; } v; v.f = f;
    unsigned int i = v.i;
    unsigned int r = (i + 0x7FFFu + ((i >> 16) & 1u)) >> 16;
    return (ushort_t)r;
}
// async global->LDS, 16B per lane; lds dest = wave-uniform base + lane*16
__device__ __forceinline__ void gload16(const ushort_t* g, ushort_t* l) {
    __builtin_amdgcn_global_load_lds((const __attribute__((address_space(1))) void*)g,
                                     (__attribute__((address_space(3))) void*)l, 16, 0, 0);
}
__device__ __forceinline__ void unp8(uint4 u, float* f) {
    const ushort_t* s = (const ushort_t*)&u;
    #pragma unroll
    for (int i = 0; i < 8; ++i) f[i] = bf2f(s[i]);
}

// ---------------------------------------------------------------------------
// x (fp32 [n][t][d]) -> g_xb (bf16, row t*256+n). grid 8192 x 128.
// ---------------------------------------------------------------------------
__global__ __launch_bounds__(128) void cvt_x(const float* __restrict__ x)
{
    int b = blockIdx.x;                 // in-row = n*32 + t
    int n = b >> 5, tt = b & 31;
    int tid = threadIdx.x;
    const float* src = x + (size_t)b * 1024 + tid * 8;
    float4 a = *(const float4*)src;
    float4 c = *(const float4*)(src + 4);
    ushort_t r[8];
    r[0]=f2bf(a.x); r[1]=f2bf(a.y); r[2]=f2bf(a.z); r[3]=f2bf(a.w);
    r[4]=f2bf(c.x); r[5]=f2bf(c.y); r[6]=f2bf(c.z); r[7]=f2bf(c.w);
    *(uint4*)(g_xb + (size_t)(tt * 256 + n) * 1024 + tid * 8) = *(const uint4*)r;
}

// ---------------------------------------------------------------------------
// A fp32 [n][h][l] -> g_Ab bf16 (same layout) + g_At bf16 [n][l][h].
// grid 256 (block per n) x 256 (4 h per thread).
// ---------------------------------------------------------------------------
__global__ __launch_bounds__(256) void cvt_a(const float* __restrict__ A)
{
    int n = blockIdx.x, tid = threadIdx.x;
    int h0 = tid * 4;
    const float* ap = A + (size_t)n * 16384;
    ushort_t tmp[4][16];
    #pragma unroll
    for (int i = 0; i < 4; ++i) {
        const float* row = ap + (size_t)(h0 + i) * 16;
        #pragma unroll
        for (int l = 0; l < 16; ++l) tmp[i][l] = f2bf(row[l]);
        ushort_t* dst = g_Ab + (size_t)n * 16384 + (size_t)(h0 + i) * 16;
        *(uint4*)dst       = *(const uint4*)&tmp[i][0];
        *(uint4*)(dst + 8) = *(const uint4*)&tmp[i][8];
    }
    #pragma unroll
    for (int l = 0; l < 16; ++l) {
        ushort_t pk[4] = { tmp[0][l], tmp[1][l], tmp[2][l], tmp[3][l] };
        *(uint2*)(g_At + (size_t)n * 16384 + (size_t)l * 1024 + h0) = *(const uint2*)pk;
    }
}

// ---------------------------------------------------------------------------
// Prepack Wx^T. grid (16,64) x 256.
// ---------------------------------------------------------------------------
__global__ __launch_bounds__(256) void prepack_wx(const float* __restrict__ Wx)
{
    __shared__ ushort_t tile[64][66];
    int k0 = blockIdx.x * 64, j0 = blockIdx.y * 64;
    int c = threadIdx.x & 63, r4 = threadIdx.x >> 6;
    for (int rr = 0; rr < 64; rr += 4) {
        int r = rr + r4;
        tile[r][c] = f2bf(Wx[(size_t)(k0 + r) * 4096 + j0 + c]);
    }
    __syncthreads();
    for (int rr = 0; rr < 64; rr += 4) {
        int j = rr + r4;
        g_Wxt[(size_t)(j0 + j) * 1024 + k0 + c] = tile[c][j];
    }
}

// ---------------------------------------------------------------------------
// Prepack [Wh^T | Wattn^T]. grid (32,64) x 256.
// ---------------------------------------------------------------------------
__global__ __launch_bounds__(256) void prepack_w2(
    const float* __restrict__ Wh, const float* __restrict__ Wattn)
{
    __shared__ ushort_t tile[64][66];
    int k0 = blockIdx.x * 64, j0 = blockIdx.y * 64;
    const float* src = (k0 < 1024) ? Wh : Wattn;
    int krel = (k0 < 1024) ? k0 : k0 - 1024;
    int c = threadIdx.x & 63, r4 = threadIdx.x >> 6;
    for (int rr = 0; rr < 64; rr += 4) {
        int r = rr + r4;
        tile[r][c] = f2bf(src[(size_t)(krel + r) * 4096 + j0 + c]);
    }
    __syncthreads();
    for (int rr = 0; rr < 64; rr += 4) {
        int j = rr + r4;
        g_W2[(size_t)(j0 + j) * 2048 + k0 + c] = tile[c][j];
    }
}

// ---------------------------------------------------------------------------
// Init: h0 = c0 = mean over 16 spatial of A. grid 1024 x 256.
// ---------------------------------------------------------------------------
__global__ __launch_bounds__(256) void init_hc(const float* __restrict__ A)
{
    int gid = blockIdx.x * 256 + threadIdx.x;       // (n,h)
    int n = gid >> 10, h = gid & 1023;
    const float* ap = A + ((size_t)gid << 4);
    float4 a0 = *(const float4*)(ap);
    float4 a1 = *(const float4*)(ap + 4);
    float4 a2 = *(const float4*)(ap + 8);
    float4 a3 = *(const float4*)(ap + 12);
    float s = (a0.x+a0.y+a0.z+a0.w) + (a1.x+a1.y+a1.z+a1.w)
            + (a2.x+a2.y+a2.z+a2.w) + (a3.x+a3.y+a3.z+a3.w);
    s *= (1.0f / 16.0f);
    g_Hc[0][n * 2048 + h] = f2bf(s);
    g_c[gid] = s;
}

// ---------------------------------------------------------------------------
// Hoisted GEMM: g_px[t*256+n][j] = x@Wx + b. M=8192, N=4096, K=1024.
// 128x128 tile, BK=64, global_load_lds(16B), 4x4 acc/wave.
// XOR-swizzled K-segments: LDS slot p of row r holds global seg p^(r&7)
// -> MFMA fragment reads are 2-way (free) instead of 16-way conflicted.
// ---------------------------------------------------------------------------
__global__ __launch_bounds__(256) void xw_gemm(const float* __restrict__ bias)
{
    __shared__ __align__(16) char smem[33280];
    ushort_t* lA = (ushort_t*)smem;                 // 128 x 64 bf16 (16 KB)
    ushort_t* lB = (ushort_t*)(smem + 16384);       // 128 x 64 bf16 (16 KB)
    float*    lP = (float*)smem;                    // 64 x 130 fp32 (epilogue alias)

    int b = blockIdx.x;
    int mb = b >> 5, jb = b & 31;
    int m0 = mb * 128, j0 = jb * 128;
    int tid = threadIdx.x, lane = tid & 63, wv = tid >> 6;
    int wm = wv >> 1, wn = wv & 1;
    int lm = lane & 15, quad = lane >> 4;

    // staging: per glds instr, 64 lanes = 8 rows x 8 segs(16B), seg swizzled
    int srow = lane >> 3, sseg = lane & 7;
    const ushort_t* gA = g_xb  + (size_t)(m0 + wv * 32 + srow) * 1024 + (sseg ^ srow) * 8;
    const ushort_t* gB = g_Wxt + (size_t)(j0 + wv * 32 + srow) * 1024 + (sseg ^ srow) * 8;

    floatx4 acc[4][4] = {};
    for (int kt = 0; kt < 16; ++kt) {
        __syncthreads();                            // prev compute done
        #pragma unroll
        for (int i = 0; i < 4; ++i) {
            gload16(gA + (size_t)i * 8 * 1024 + kt * 64, lA + (wv * 32 + i * 8) * 64);
            gload16(gB + (size_t)i * 8 * 1024 + kt * 64, lB + (wv * 32 + i * 8) * 64);
        }
        __syncthreads();                            // vmcnt drained: tile ready
        #pragma unroll
        for (int ks = 0; ks < 2; ++ks) {
            short8 af[4], bf[4];
            #pragma unroll
            for (int i = 0; i < 4; ++i) {
                int row = wm*64 + i*16 + lm;
                af[i] = *(const short8*)(lA + row * 64 + (((ks*4 + quad) ^ (row & 7)) * 8));
            }
            #pragma unroll
            for (int j = 0; j < 4; ++j) {
                int row = wn*64 + j*16 + lm;
                bf[j] = *(const short8*)(lB + row * 64 + (((ks*4 + quad) ^ (row & 7)) * 8));
            }
            #pragma unroll
            for (int i = 0; i < 4; ++i)
                #pragma unroll
                for (int j = 0; j < 4; ++j)
                    acc[i][j] = __builtin_amdgcn_mfma_f32_16x16x32_bf16(af[i], bf[j], acc[i][j], 0, 0, 0);
        }
    }

    // epilogue: 2 phases of 64 rows; LDS-transpose then dense float4 stores
    #pragma unroll
    for (int ph = 0; ph < 2; ++ph) {
        __syncthreads();
        if (wm == ph) {
            #pragma unroll
            for (int i = 0; i < 4; ++i)
                #pragma unroll
                for (int j = 0; j < 4; ++j)
                    #pragma unroll
                    for (int q = 0; q < 4; ++q)
                        lP[(i*16 + quad*4 + q) * 130 + wn*64 + j*16 + lm] = acc[i][j][q];
        }
        __syncthreads();
        int row = tid >> 2, seg = tid & 3;
        const float* src = lP + row * 130 + seg * 32;
        float* dst = g_px + (size_t)(m0 + ph * 64 + row) * 4096 + j0 + seg * 32;
        const float* bb = bias + j0 + seg * 32;
        #pragma unroll
        for (int i = 0; i < 8; ++i) {
            float4 v = *(const float4*)(src + i * 4);
            float4 w = *(const float4*)(bb + i * 4);
            v.x += w.x; v.y += w.y; v.z += w.z; v.w += w.w;
            *(float4*)(dst + i * 4) = v;
        }
    }
}

// ---------------------------------------------------------------------------
// Attention step: logits from g_At (coalesced in h), softmax, weighted sum
// from g_Ab. grid 256 (block per n) x 256.
// ---------------------------------------------------------------------------
__global__ __launch_bounds__(256) void attn_step(int t)
{
    ushort_t* Hc = g_Hc[t & 1];
    int n = blockIdx.x, tid = threadIdx.x;
    int lane = tid & 63, wv = tid >> 6;
    const ushort_t* hp = Hc + n * 2048;

    int hc = lane * 16;
    float hv[16];
    unp8(*(const uint4*)(hp + hc), hv);
    unp8(*(const uint4*)(hp + hc + 8), hv + 8);

    __shared__ float red[16];
    float lg[4];
    #pragma unroll
    for (int l4 = 0; l4 < 4; ++l4) {
        int l = wv * 4 + l4;
        const ushort_t* ar = g_At + (size_t)n * 16384 + (size_t)l * 1024 + hc;
        float av[16];
        unp8(*(const uint4*)ar, av);
        unp8(*(const uint4*)(ar + 8), av + 8);
        float s = 0.f;
        #pragma unroll
        for (int i = 0; i < 16; ++i) s += hv[i] * av[i];
        s += __shfl_xor(s, 32); s += __shfl_xor(s, 16); s += __shfl_xor(s, 8);
        s += __shfl_xor(s, 4);  s += __shfl_xor(s, 2);  s += __shfl_xor(s, 1);
        lg[l4] = s;
    }
    if (lane == 0) {
        #pragma unroll
        for (int l4 = 0; l4 < 4; ++l4) red[wv * 4 + l4] = lg[l4];
    }
    __syncthreads();
    float w[16], mx = -1e30f;
    #pragma unroll
    for (int l = 0; l < 16; ++l) {
        float s = red[l] * 0.03125f;
        w[l] = s; mx = fmaxf(mx, s);
    }
    float sum = 0.f;
    #pragma unroll
    for (int l = 0; l < 16; ++l) { w[l] = __expf(w[l] - mx); sum += w[l]; }
    float inv = 1.f / sum;
    #pragma unroll
    for (int l = 0; l < 16; ++l) w[l] *= inv;

    int h0 = tid * 4;
    const ushort_t* ab = g_Ab + (size_t)n * 16384 + (size_t)h0 * 16;
    ushort_t outp[4];
    #pragma unroll
    for (int i = 0; i < 4; ++i) {
        float av[16];
        unp8(*(const uint4*)(ab + i * 16), av);
        unp8(*(const uint4*)(ab + i * 16 + 8), av + 8);
        float acc = 0.f;
        #pragma unroll
        for (int l = 0; l < 16; ++l) acc += av[l] * w[l];
        outp[i] = f2bf(acc);
    }
    *(uint2*)(Hc + n * 2048 + 1024 + h0) = *(const uint2*)outp;
}

// ---------------------------------------------------------------------------
// Per-step GEMM: C[256x4096] = [h|attn] @ [Wh;Wattn] (K=2048) + px + LSTM.
// 256 blocks (XCD-pinned j-strips), 4 waves. 64x64 tile, BK=128,
// double-buffered global_load_lds; wave owns a k-quarter, 4x4 acc;
// LDS-atomic reduce. XOR-swizzled segs: slot p of row r holds seg p^(r&15)
// -> fragment reads 2-way (free) instead of 16-way conflicted.
// ---------------------------------------------------------------------------
__global__ __launch_bounds__(256) void step_gemm(float* __restrict__ out, int t)
{
    __shared__ __align__(16) ushort_t lA[2][64 * 128];
    __shared__ __align__(16) ushort_t lB[2][64 * 128];
    __shared__ float lP[64 * 65];

    const ushort_t* Hin  = g_Hc[t & 1];
    ushort_t*       Hout = g_Hc[(t + 1) & 1];

    int b = blockIdx.x;
    int xcd = b & 7, r = b >> 3;
    int mt_ = r & 3, jt = xcd * 8 + (r >> 2);
    int n0 = mt_ * 64, hh0 = jt * 16;
    int tid = threadIdx.x, lane = tid & 63, wv = tid >> 6;
    int lm = lane & 15, quad = lane >> 4;

    for (int i = tid; i < 64 * 65; i += 256) lP[i] = 0.f;

    // staging: per glds instr, 64 lanes = 4 rows x 16 segs(16B), seg swizzled.
    // Wave wv stages tile rows [wv*16, wv*16+16) of A and B.
    int srow = lane >> 4, sseg = lane & 15;
    const ushort_t* gA0 = Hin  + (size_t)(n0 + wv * 16 + srow) * 2048;
    const ushort_t* gB0 = g_W2 + (size_t)(wv * 1024 + hh0 + srow) * 2048;

    floatx4 acc[4][4] = {};
    int segk = wv * 4 + quad;          // this wave's k-quarter: segs wv*4..wv*4+3

    // prologue: stage tile 0
    #pragma unroll
    for (int i = 0; i < 4; ++i) {
        int rlow = i * 4 + srow;       // tile-row & 15
        gload16(gA0 + (size_t)i * 4 * 2048 + (sseg ^ rlow) * 8, &lA[0][(wv * 16 + i * 4) * 128]);
        gload16(gB0 + (size_t)i * 4 * 2048 + (sseg ^ rlow) * 8, &lB[0][(wv * 16 + i * 4) * 128]);
    }
    __syncthreads();

    for (int it = 0; it < 16; ++it) {
        if (it < 15) {
            int p = (it + 1) & 1, kk = (it + 1) * 128;
            #pragma unroll
            for (int i = 0; i < 4; ++i) {
                int rlow = i * 4 + srow;
                gload16(gA0 + (size_t)i * 4 * 2048 + kk + (sseg ^ rlow) * 8, &lA[p][(wv * 16 + i * 4) * 128]);
                gload16(gB0 + (size_t)i * 4 * 2048 + kk + (sseg ^ rlow) * 8, &lB[p][(wv * 16 + i * 4) * 128]);
            }
        }
        int p = it & 1;
        short8 af[4], bf[4];
        #pragma unroll
        for (int i = 0; i < 4; ++i)
            af[i] = *(const short8*)(&lA[p][(i * 16 + lm) * 128 + ((segk ^ lm) * 8)]);
        #pragma unroll
        for (int j = 0; j < 4; ++j)
            bf[j] = *(const short8*)(&lB[p][(j * 16 + lm) * 128 + ((segk ^ lm) * 8)]);
        #pragma unroll
        for (int i = 0; i < 4; ++i)
            #pragma unroll
            for (int j = 0; j < 4; ++j)
                acc[i][j] = __builtin_amdgcn_mfma_f32_16x16x32_bf16(af[i], bf[j], acc[i][j], 0, 0, 0);
        __syncthreads();   // orders prefetch-writes (vmcnt) + ds reads
    }

    // reduce 4 waves' k-partials
    #pragma unroll
    for (int i = 0; i < 4; ++i)
        #pragma unroll
        for (int j = 0; j < 4; ++j)
            #pragma unroll
            for (int q = 0; q < 4; ++q)
                atomicAdd(&lP[(i * 16 + quad * 4 + q) * 65 + j * 16 + lm], acc[i][j][q]);
    __syncthreads();

    // LSTM pointwise (preact = lP + g_px)
    #pragma unroll
    for (int q = 0; q < 4; ++q) {
        int idx = tid + q * 256;           // (nl, hl)
        int nl = idx >> 4, hl = idx & 15;
        const float* px = g_px + ((size_t)t * 256 + (n0 + nl)) * 4096 + hh0 + hl;
        float ai  = lP[nl * 65 +      hl] + px[0];
        float afv = lP[nl * 65 + 16 + hl] + px[1024];
        float ao  = lP[nl * 65 + 32 + hl] + px[2048];
        float ag  = lP[nl * 65 + 48 + hl] + px[3072];
        float iv = 1.f / (1.f + __expf(-ai));
        float fv = 1.f / (1.f + __expf(-afv));
        float ov = 1.f / (1.f + __expf(-ao));
        float gv = tanhf(ag);
        int ng = n0 + nl, hg = hh0 + hl;
        float cold = g_c[ng * 1024 + hg];
        float cnew = fv * cold + iv * gv;
        float hnew = ov * tanhf(cnew);
        g_c[ng * 1024 + hg] = cnew;
        Hout[ng * 2048 + hg] = f2bf(hnew);
        out[(size_t)ng * (T_SEQ * HH) + (size_t)t * HH + hg] = hnew;
    }
}

// ---------------------------------------------------------------------------
extern "C" void kernel_launch(void* const* d_in, const int* in_sizes, int n_in,
                              void* d_out, int out_size, void* d_ws, size_t ws_size,
                              hipStream_t stream) {
    const float* x     = (const float*)d_in[0];
    const float* A     = (const float*)d_in[1];
    const float* Wx    = (const float*)d_in[2];
    const float* Wh    = (const float*)d_in[3];
    const float* Wattn = (const float*)d_in[4];
    const float* bias  = (const float*)d_in[5];
    float* out = (float*)d_out;

    cvt_x<<<8192, 128, 0, stream>>>(x);
    cvt_a<<<256, 256, 0, stream>>>(A);
    prepack_wx<<<dim3(16, 64), 256, 0, stream>>>(Wx);
    prepack_w2<<<dim3(32, 64), 256, 0, stream>>>(Wh, Wattn);
    init_hc<<<1024, 256, 0, stream>>>(A);
    xw_gemm<<<2048, 256, 0, stream>>>(bias);
    for (int t = 0; t < T_SEQ; ++t) {
        attn_step<<<256, 256, 0, stream>>>(t);
        step_gemm<<<256, 256, 0, stream>>>(out, t);
    }
}

// Round 6
// 990.806 us; speedup vs baseline: 3.4437x; 1.8493x over previous
//
#include <hip/hip_runtime.h>

#define N_B 256
#define T_SEQ 32
#define DD 1024
#define HH 1024

typedef short short8 __attribute__((ext_vector_type(8)));
typedef float floatx4 __attribute__((ext_vector_type(4)));
typedef unsigned short ushort_t;

// ---- scratch as device globals (no dependence on ws_size) ------------------
__device__ __align__(16) ushort_t g_Wxt[(size_t)4096 * 1024];      // 8 MB  [j][k]=Wx^T
__device__ __align__(16) ushort_t g_W2 [(size_t)4096 * 2048];      // 16 MB [j][k]=[Wh^T|Wattn^T]
__device__ __align__(16) ushort_t g_xb [(size_t)8192 * 1024];      // 16 MB bf16 x, row = t*256+n
__device__ __align__(16) float    g_px [(size_t)8192 * 4096];      // 134 MB fp32, row = t*256+n
__device__ __align__(16) ushort_t g_Ab [(size_t)N_B * 16384];      // 8 MB bf16 A [n][h][l]
__device__ __align__(16) ushort_t g_At [(size_t)N_B * 16384];      // 8 MB bf16 A [n][l][h]
__device__ __align__(16) ushort_t g_Hc[2][N_B * 2048];             // [h|attn] bf16 ping-pong
__device__ __align__(16) float    g_c [N_B * HH];                  // fp32 cell state

__device__ __forceinline__ float bf2f(ushort_t u){
    union { unsigned int i; float f; } v; v.i = ((unsigned int)u) << 16; return v.f;
}
__device__ __forceinline__ ushort_t f2bf(float f){
    union { unsigned int i; float f; } v; v.f = f;
    unsigned int i = v.i;
    unsigned int r = (i + 0x7FFFu + ((i >> 16) & 1u)) >> 16;
    return (ushort_t)r;
}
// async global->LDS, 16B per lane; lds dest = wave-uniform base + lane*16
__device__ __forceinline__ void gload16(const ushort_t* g, ushort_t* l) {
    __builtin_amdgcn_global_load_lds((const __attribute__((address_space(1))) void*)g,
                                     (__attribute__((address_space(3))) void*)l, 16, 0, 0);
}
__device__ __forceinline__ void unp8(uint4 u, float* f) {
    const ushort_t* s = (const ushort_t*)&u;
    #pragma unroll
    for (int i = 0; i < 8; ++i) f[i] = bf2f(s[i]);
}

// ---------------------------------------------------------------------------
// x (fp32 [n][t][d]) -> g_xb (bf16, row t*256+n). grid 8192 x 128.
// ---------------------------------------------------------------------------
__global__ __launch_bounds__(128) void cvt_x(const float* __restrict__ x)
{
    int b = blockIdx.x;                 // in-row = n*32 + t
    int n = b >> 5, tt = b & 31;
    int tid = threadIdx.x;
    const float* src = x + (size_t)b * 1024 + tid * 8;
    float4 a = *(const float4*)src;
    float4 c = *(const float4*)(src + 4);
    ushort_t r[8];
    r[0]=f2bf(a.x); r[1]=f2bf(a.y); r[2]=f2bf(a.z); r[3]=f2bf(a.w);
    r[4]=f2bf(c.x); r[5]=f2bf(c.y); r[6]=f2bf(c.z); r[7]=f2bf(c.w);
    *(uint4*)(g_xb + (size_t)(tt * 256 + n) * 1024 + tid * 8) = *(const uint4*)r;
}

// ---------------------------------------------------------------------------
// A fp32 [n][h][l] -> g_Ab bf16 (same layout) + g_At bf16 [n][l][h].
// grid 256 x 256.
// ---------------------------------------------------------------------------
__global__ __launch_bounds__(256) void cvt_a(const float* __restrict__ A)
{
    int n = blockIdx.x, tid = threadIdx.x;
    int h0 = tid * 4;
    const float* ap = A + (size_t)n * 16384;
    ushort_t tmp[4][16];
    #pragma unroll
    for (int i = 0; i < 4; ++i) {
        const float* row = ap + (size_t)(h0 + i) * 16;
        #pragma unroll
        for (int l = 0; l < 16; ++l) tmp[i][l] = f2bf(row[l]);
        ushort_t* dst = g_Ab + (size_t)n * 16384 + (size_t)(h0 + i) * 16;
        *(uint4*)dst       = *(const uint4*)&tmp[i][0];
        *(uint4*)(dst + 8) = *(const uint4*)&tmp[i][8];
    }
    #pragma unroll
    for (int l = 0; l < 16; ++l) {
        ushort_t pk[4] = { tmp[0][l], tmp[1][l], tmp[2][l], tmp[3][l] };
        *(uint2*)(g_At + (size_t)n * 16384 + (size_t)l * 1024 + h0) = *(const uint2*)pk;
    }
}

// ---------------------------------------------------------------------------
// Prepack Wx^T. grid (16,64) x 256.
// ---------------------------------------------------------------------------
__global__ __launch_bounds__(256) void prepack_wx(const float* __restrict__ Wx)
{
    __shared__ ushort_t tile[64][66];
    int k0 = blockIdx.x * 64, j0 = blockIdx.y * 64;
    int c = threadIdx.x & 63, r4 = threadIdx.x >> 6;
    for (int rr = 0; rr < 64; rr += 4) {
        int r = rr + r4;
        tile[r][c] = f2bf(Wx[(size_t)(k0 + r) * 4096 + j0 + c]);
    }
    __syncthreads();
    for (int rr = 0; rr < 64; rr += 4) {
        int j = rr + r4;
        g_Wxt[(size_t)(j0 + j) * 1024 + k0 + c] = tile[c][j];
    }
}

// ---------------------------------------------------------------------------
// Prepack [Wh^T | Wattn^T]. grid (32,64) x 256.
// ---------------------------------------------------------------------------
__global__ __launch_bounds__(256) void prepack_w2(
    const float* __restrict__ Wh, const float* __restrict__ Wattn)
{
    __shared__ ushort_t tile[64][66];
    int k0 = blockIdx.x * 64, j0 = blockIdx.y * 64;
    const float* src = (k0 < 1024) ? Wh : Wattn;
    int krel = (k0 < 1024) ? k0 : k0 - 1024;
    int c = threadIdx.x & 63, r4 = threadIdx.x >> 6;
    for (int rr = 0; rr < 64; rr += 4) {
        int r = rr + r4;
        tile[r][c] = f2bf(src[(size_t)(krel + r) * 4096 + j0 + c]);
    }
    __syncthreads();
    for (int rr = 0; rr < 64; rr += 4) {
        int j = rr + r4;
        g_W2[(size_t)(j0 + j) * 2048 + k0 + c] = tile[c][j];
    }
}

// ---------------------------------------------------------------------------
// Init: h0 = c0 = mean over 16 spatial of A. grid 1024 x 256.
// ---------------------------------------------------------------------------
__global__ __launch_bounds__(256) void init_hc(const float* __restrict__ A)
{
    int gid = blockIdx.x * 256 + threadIdx.x;       // (n,h)
    int n = gid >> 10, h = gid & 1023;
    const float* ap = A + ((size_t)gid << 4);
    float4 a0 = *(const float4*)(ap);
    float4 a1 = *(const float4*)(ap + 4);
    float4 a2 = *(const float4*)(ap + 8);
    float4 a3 = *(const float4*)(ap + 12);
    float s = (a0.x+a0.y+a0.z+a0.w) + (a1.x+a1.y+a1.z+a1.w)
            + (a2.x+a2.y+a2.z+a2.w) + (a3.x+a3.y+a3.z+a3.w);
    s *= (1.0f / 16.0f);
    g_Hc[0][n * 2048 + h] = f2bf(s);
    g_c[gid] = s;
}

// ---------------------------------------------------------------------------
// Hoisted GEMM: g_px[t*256+n][j] = x@Wx + b. M=8192, N=4096, K=1024.
// 128x128 tile, BK=64, global_load_lds(16B), 4x4 acc/wave, XOR seg-swizzle.
// ---------------------------------------------------------------------------
__global__ __launch_bounds__(256) void xw_gemm(const float* __restrict__ bias)
{
    __shared__ __align__(16) char smem[33280];
    ushort_t* lA = (ushort_t*)smem;                 // 128 x 64 bf16 (16 KB)
    ushort_t* lB = (ushort_t*)(smem + 16384);       // 128 x 64 bf16 (16 KB)
    float*    lP = (float*)smem;                    // 64 x 130 fp32 (epilogue alias)

    int b = blockIdx.x;
    int mb = b >> 5, jb = b & 31;
    int m0 = mb * 128, j0 = jb * 128;
    int tid = threadIdx.x, lane = tid & 63, wv = tid >> 6;
    int wm = wv >> 1, wn = wv & 1;
    int lm = lane & 15, quad = lane >> 4;

    // staging: per glds instr, 64 lanes = 8 rows x 8 segs(16B), seg swizzled
    int srow = lane >> 3, sseg = lane & 7;
    const ushort_t* gA = g_xb  + (size_t)(m0 + wv * 32 + srow) * 1024 + (sseg ^ srow) * 8;
    const ushort_t* gB = g_Wxt + (size_t)(j0 + wv * 32 + srow) * 1024 + (sseg ^ srow) * 8;

    floatx4 acc[4][4] = {};
    for (int kt = 0; kt < 16; ++kt) {
        __syncthreads();                            // prev compute done
        #pragma unroll
        for (int i = 0; i < 4; ++i) {
            gload16(gA + (size_t)i * 8 * 1024 + kt * 64, lA + (wv * 32 + i * 8) * 64);
            gload16(gB + (size_t)i * 8 * 1024 + kt * 64, lB + (wv * 32 + i * 8) * 64);
        }
        __syncthreads();                            // vmcnt drained: tile ready
        #pragma unroll
        for (int ks = 0; ks < 2; ++ks) {
            short8 af[4], bf[4];
            #pragma unroll
            for (int i = 0; i < 4; ++i) {
                int row = wm*64 + i*16 + lm;
                af[i] = *(const short8*)(lA + row * 64 + (((ks*4 + quad) ^ (row & 7)) * 8));
            }
            #pragma unroll
            for (int j = 0; j < 4; ++j) {
                int row = wn*64 + j*16 + lm;
                bf[j] = *(const short8*)(lB + row * 64 + (((ks*4 + quad) ^ (row & 7)) * 8));
            }
            #pragma unroll
            for (int i = 0; i < 4; ++i)
                #pragma unroll
                for (int j = 0; j < 4; ++j)
                    acc[i][j] = __builtin_amdgcn_mfma_f32_16x16x32_bf16(af[i], bf[j], acc[i][j], 0, 0, 0);
        }
    }

    // epilogue: 2 phases of 64 rows; LDS-transpose then dense float4 stores
    #pragma unroll
    for (int ph = 0; ph < 2; ++ph) {
        __syncthreads();
        if (wm == ph) {
            #pragma unroll
            for (int i = 0; i < 4; ++i)
                #pragma unroll
                for (int j = 0; j < 4; ++j)
                    #pragma unroll
                    for (int q = 0; q < 4; ++q)
                        lP[(i*16 + quad*4 + q) * 130 + wn*64 + j*16 + lm] = acc[i][j][q];
        }
        __syncthreads();
        int row = tid >> 2, seg = tid & 3;
        const float* src = lP + row * 130 + seg * 32;
        float* dst = g_px + (size_t)(m0 + ph * 64 + row) * 4096 + j0 + seg * 32;
        const float* bb = bias + j0 + seg * 32;
        #pragma unroll
        for (int i = 0; i < 8; ++i) {
            float4 v = *(const float4*)(src + i * 4);
            float4 w = *(const float4*)(bb + i * 4);
            v.x += w.x; v.y += w.y; v.z += w.z; v.w += w.w;
            *(float4*)(dst + i * 4) = v;
        }
    }
}

// ---------------------------------------------------------------------------
// Attention step: logits from g_At, softmax, weighted sum from g_Ab.
// grid 256 (block per n) x 256.
// ---------------------------------------------------------------------------
__global__ __launch_bounds__(256) void attn_step(int t)
{
    ushort_t* Hc = g_Hc[t & 1];
    int n = blockIdx.x, tid = threadIdx.x;
    int lane = tid & 63, wv = tid >> 6;
    const ushort_t* hp = Hc + n * 2048;

    int hc = lane * 16;
    float hv[16];
    unp8(*(const uint4*)(hp + hc), hv);
    unp8(*(const uint4*)(hp + hc + 8), hv + 8);

    __shared__ float red[16];
    float lg[4];
    #pragma unroll
    for (int l4 = 0; l4 < 4; ++l4) {
        int l = wv * 4 + l4;
        const ushort_t* ar = g_At + (size_t)n * 16384 + (size_t)l * 1024 + hc;
        float av[16];
        unp8(*(const uint4*)ar, av);
        unp8(*(const uint4*)(ar + 8), av + 8);
        float s = 0.f;
        #pragma unroll
        for (int i = 0; i < 16; ++i) s += hv[i] * av[i];
        s += __shfl_xor(s, 32); s += __shfl_xor(s, 16); s += __shfl_xor(s, 8);
        s += __shfl_xor(s, 4);  s += __shfl_xor(s, 2);  s += __shfl_xor(s, 1);
        lg[l4] = s;
    }
    if (lane == 0) {
        #pragma unroll
        for (int l4 = 0; l4 < 4; ++l4) red[wv * 4 + l4] = lg[l4];
    }
    __syncthreads();
    float w[16], mx = -1e30f;
    #pragma unroll
    for (int l = 0; l < 16; ++l) {
        float s = red[l] * 0.03125f;
        w[l] = s; mx = fmaxf(mx, s);
    }
    float sum = 0.f;
    #pragma unroll
    for (int l = 0; l < 16; ++l) { w[l] = __expf(w[l] - mx); sum += w[l]; }
    float inv = 1.f / sum;
    #pragma unroll
    for (int l = 0; l < 16; ++l) w[l] *= inv;

    int h0 = tid * 4;
    const ushort_t* ab = g_Ab + (size_t)n * 16384 + (size_t)h0 * 16;
    ushort_t outp[4];
    #pragma unroll
    for (int i = 0; i < 4; ++i) {
        float av[16];
        unp8(*(const uint4*)(ab + i * 16), av);
        unp8(*(const uint4*)(ab + i * 16 + 8), av + 8);
        float acc = 0.f;
        #pragma unroll
        for (int l = 0; l < 16; ++l) acc += av[l] * w[l];
        outp[i] = f2bf(acc);
    }
    *(uint2*)(Hc + n * 2048 + 1024 + h0) = *(const uint2*)outp;
}

// ---------------------------------------------------------------------------
// Per-step GEMM v3: C[256x4096] = [h|attn] @ [Wh;Wattn] (K=2048) + px + LSTM.
// Grid 512 = 8 n-tiles x 64 gate-grouped j-strips, XCD-pinned -> 2 blocks/CU
// co-resident (LDS 59 KB). 4 waves; K-split 4 (512 k each), 2x4 frag tiles
// (6 ds_read : 8 MFMA); single-buffer BK=128, XOR seg-swizzle; cross-wave
// reduce via 4 disjoint lP copies (plain ds_write, NO atomics) + 4-way sum
// in the fused LSTM epilogue.
// ---------------------------------------------------------------------------
__global__ __launch_bounds__(256, 2) void step_gemm(float* __restrict__ out, int t)
{
    __shared__ __align__(16) ushort_t lA[32 * 128];        // 8 KB
    __shared__ __align__(16) ushort_t lB[64 * 128];        // 16 KB
    __shared__ float lP[4][32 * 68];                       // 34.8 KB

    const ushort_t* Hin  = g_Hc[t & 1];
    ushort_t*       Hout = g_Hc[(t + 1) & 1];

    int b = blockIdx.x;
    int xcd = b & 7, r = b >> 3;
    int jt = xcd * 8 + (r & 7), nt = r >> 3;
    int n0 = nt * 32, hh0 = jt * 16;
    int tid = threadIdx.x, lane = tid & 63, wv = tid >> 6;
    int lm = lane & 15, quad = lane >> 4;

    // staging: per glds instr, 64 lanes = 4 rows x 16 segs(16B), seg swizzled.
    int srow = lane >> 4, sseg = lane & 15;
    // A: wave wv stages rows wv*8 .. wv*8+8 (2 instr)
    // B: wave wv stages rows wv*16 .. wv*16+16 (4 instr); row jrow -> gate wv
    const ushort_t* gA0 = Hin  + (size_t)(n0 + wv * 8 + srow) * 2048;
    const ushort_t* gB0 = g_W2 + (size_t)(wv * 1024 + hh0 + srow) * 2048;

    floatx4 acc[2][4] = {};
    int segk = wv * 4 + quad;          // wave's k-slice: seg wv*4+quad of each chunk

    for (int it = 0; it < 16; ++it) {
        int kk = it * 128;
        __syncthreads();               // prev reads done
        #pragma unroll
        for (int i = 0; i < 2; ++i) {
            int rlow = (wv * 8 + i * 4 + srow) & 15;
            gload16(gA0 + (size_t)i * 4 * 2048 + kk + (sseg ^ rlow) * 8,
                    lA + (wv * 8 + i * 4) * 128);
        }
        #pragma unroll
        for (int i = 0; i < 4; ++i) {
            int rlow = i * 4 + srow;   // (wv*16 + i*4 + srow) & 15
            gload16(gB0 + (size_t)i * 4 * 2048 + kk + (sseg ^ rlow) * 8,
                    lB + (wv * 16 + i * 4) * 128);
        }
        __syncthreads();               // vmcnt drained: tile ready
        short8 af[2], bf[4];
        #pragma unroll
        for (int i = 0; i < 2; ++i)
            af[i] = *(const short8*)(lA + (i * 16 + lm) * 128 + ((segk ^ lm) * 8));
        #pragma unroll
        for (int j = 0; j < 4; ++j)
            bf[j] = *(const short8*)(lB + (j * 16 + lm) * 128 + ((segk ^ lm) * 8));
        #pragma unroll
        for (int i = 0; i < 2; ++i)
            #pragma unroll
            for (int j = 0; j < 4; ++j)
                acc[i][j] = __builtin_amdgcn_mfma_f32_16x16x32_bf16(af[i], bf[j], acc[i][j], 0, 0, 0);
    }

    // plain-store partials: wave-private lP copy (no atomics)
    __syncthreads();
    float* my = &lP[wv][0];
    #pragma unroll
    for (int i = 0; i < 2; ++i)
        #pragma unroll
        for (int j = 0; j < 4; ++j)
            #pragma unroll
            for (int q = 0; q < 4; ++q)
                my[(i * 16 + quad * 4 + q) * 68 + j * 16 + lm] = acc[i][j][q];
    __syncthreads();

    // LSTM pointwise: preact = sum of 4 wave-partials + g_px
    #pragma unroll
    for (int e = 0; e < 2; ++e) {
        int idx = tid + e * 256;           // 0..511 = (nl, hl)
        int nl = idx >> 4, hl = idx & 15;
        int base = nl * 68 + hl;
        float s0 = lP[0][base]      + lP[1][base]      + lP[2][base]      + lP[3][base];
        float s1 = lP[0][base + 16] + lP[1][base + 16] + lP[2][base + 16] + lP[3][base + 16];
        float s2 = lP[0][base + 32] + lP[1][base + 32] + lP[2][base + 32] + lP[3][base + 32];
        float s3 = lP[0][base + 48] + lP[1][base + 48] + lP[2][base + 48] + lP[3][base + 48];
        const float* px = g_px + ((size_t)t * 256 + (n0 + nl)) * 4096 + hh0 + hl;
        float ai  = s0 + px[0];
        float afv = s1 + px[1024];
        float ao  = s2 + px[2048];
        float ag  = s3 + px[3072];
        float iv = 1.f / (1.f + __expf(-ai));
        float fv = 1.f / (1.f + __expf(-afv));
        float ov = 1.f / (1.f + __expf(-ao));
        float gv = tanhf(ag);
        int ng = n0 + nl, hg = hh0 + hl;
        float cold = g_c[ng * 1024 + hg];
        float cnew = fv * cold + iv * gv;
        float hnew = ov * tanhf(cnew);
        g_c[ng * 1024 + hg] = cnew;
        Hout[ng * 2048 + hg] = f2bf(hnew);
        out[(size_t)ng * (T_SEQ * HH) + (size_t)t * HH + hg] = hnew;
    }
}

// ---------------------------------------------------------------------------
extern "C" void kernel_launch(void* const* d_in, const int* in_sizes, int n_in,
                              void* d_out, int out_size, void* d_ws, size_t ws_size,
                              hipStream_t stream) {
    const float* x     = (const float*)d_in[0];
    const float* A     = (const float*)d_in[1];
    const float* Wx    = (const float*)d_in[2];
    const float* Wh    = (const float*)d_in[3];
    const float* Wattn = (const float*)d_in[4];
    const float* bias  = (const float*)d_in[5];
    float* out = (float*)d_out;

    cvt_x<<<8192, 128, 0, stream>>>(x);
    cvt_a<<<256, 256, 0, stream>>>(A);
    prepack_wx<<<dim3(16, 64), 256, 0, stream>>>(Wx);
    prepack_w2<<<dim3(32, 64), 256, 0, stream>>>(Wh, Wattn);
    init_hc<<<1024, 256, 0, stream>>>(A);
    xw_gemm<<<2048, 256, 0, stream>>>(bias);
    for (int t = 0; t < T_SEQ; ++t) {
        attn_step<<<256, 256, 0, stream>>>(t);
        step_gemm<<<512, 256, 0, stream>>>(out, t);
    }
}